// Round 7
// baseline (60.459 us; speedup 1.0000x reference)
//
#include <hip/hip_runtime.h>
#include <math.h>

// LocalGroupedZernikeNewBP: fused grouped soft-abs + 3x3 box gain + tanh.
// Layout [B=8, H=256, W=256, C=36] fp32, channel-last.
// Groups: special 0..2 (plain tanh), low 3..5, mid 6..14, high 15..35.
//
// R7: two barrier-free streaming kernels; gains computed in-wave (no gains
// array, no third kernel).
//  K1: per-pixel group sums. Wave lanes 0..62 own 63 consecutive float4 =
//      7 pixels x 9 quads; segmented shfl_down reduce; heads store
//      float4(lo,mi,hi,0) to d_ws. Proven ~4.5 us.
//  K2: same lane geometry, single sweep. Heads (j==0) read 3x3 sums
//      neighborhood (cache-hot), compute folded gains, shfl-broadcast to
//      their 8 peers; all lanes transform their float4 and store coalesced.

static constexpr int IMG = 256;
static constexpr int NB = 8;
static constexpr int NPIX = NB * IMG * IMG;   // 524288

__global__ __launch_bounds__(256) void k1_sums(
    const float4* __restrict__ in4, float4* __restrict__ sums,
    const float* __restrict__ pb_lo, const float* __restrict__ pe_lo,
    const float* __restrict__ pb_mi, const float* __restrict__ pe_mi,
    const float* __restrict__ pb_hi, const float* __restrict__ pe_hi)
{
    const float b_lo = pb_lo[0], e_lo = pe_lo[0];
    const float b_mi = pb_mi[0], e_mi = pe_mi[0];
    const float b_hi = pb_hi[0], e_hi = pe_hi[0];

    const int lane = threadIdx.x & 63;
    const int j = lane % 9;                 // quad within pixel
    const bool act = lane < 63;             // lane 63 idle
    const int sub = lane / 9;               // pixel offset within wave's 7
    const int c0 = 4 * j;

    float biasK[4], epsK[4], mLo[4], mMi[4], mHi[4];
    #pragma unroll
    for (int k = 0; k < 4; ++k) {
        const int c = c0 + k;
        biasK[k] = c < 3 ? 0.f : (c < 6 ? b_lo : (c < 15 ? b_mi : b_hi));
        epsK[k]  = c < 6 ? e_lo : (c < 15 ? e_mi : e_hi);
        mLo[k] = (c >= 3 && c < 6) ? 1.f : 0.f;
        mMi[k] = (c >= 6 && c < 15) ? 1.f : 0.f;
        mHi[k] = (c >= 15) ? 1.f : 0.f;
    }

    const int wid = blockIdx.x * (blockDim.x >> 6) + (threadIdx.x >> 6);
    const int nw  = gridDim.x * (blockDim.x >> 6);

    for (int pix0 = wid * 7; pix0 < NPIX; pix0 += nw * 7) {
        const int myPix = pix0 + sub;
        float4 x = make_float4(0.f, 0.f, 0.f, 0.f);
        if (act && myPix < NPIX) x = in4[pix0 * 9 + lane];

        const float xs[4] = {x.x, x.y, x.z, x.w};
        float t[4];
        #pragma unroll
        for (int k = 0; k < 4; ++k) {
            const float u = xs[k] + biasK[k];
            t[k] = sqrtf(fmaf(u, u, epsK[k]));
        }
        float pl = 0.f, pm = 0.f, ph = 0.f;
        #pragma unroll
        for (int k = 0; k < 4; ++k) {
            pl = fmaf(mLo[k], t[k], pl);
            pm = fmaf(mMi[k], t[k], pm);
            ph = fmaf(mHi[k], t[k], ph);
        }
        // segmented reduction: after d=1,2,4,8 lane j covers [j, min(j+2d-1,8)]
        #pragma unroll
        for (int d = 1; d < 16; d <<= 1) {
            const float al = __shfl_down(pl, d);
            const float am = __shfl_down(pm, d);
            const float ah = __shfl_down(ph, d);
            if (j + d < 9) { pl += al; pm += am; ph += ah; }
        }
        if (act && j == 0 && myPix < NPIX)     // lane 63 must NOT store
            sums[myPix] = make_float4(pl, pm, ph, 0.f);
    }
}

__global__ __launch_bounds__(256) void k2_out(
    const float4* __restrict__ in4, const float4* __restrict__ sums,
    float4* __restrict__ out4,
    const float* __restrict__ p_sp_bias, const float* __restrict__ p_sp_alpha,
    const float* __restrict__ p_sp_amax,
    const float* __restrict__ p_lo_bias, const float* __restrict__ p_lo_alpha,
    const float* __restrict__ p_lo_amax, const float* __restrict__ p_lo_gss,
    const float* __restrict__ p_lo_psat,
    const float* __restrict__ p_mi_bias, const float* __restrict__ p_mi_alpha,
    const float* __restrict__ p_mi_amax, const float* __restrict__ p_mi_gss,
    const float* __restrict__ p_mi_psat,
    const float* __restrict__ p_hi_bias, const float* __restrict__ p_hi_alpha,
    const float* __restrict__ p_hi_amax, const float* __restrict__ p_hi_gss,
    const float* __restrict__ p_hi_psat)
{
    const int lane = threadIdx.x & 63;
    const int j = lane % 9;
    const bool act = lane < 63;
    const int sub = lane / 9;
    const int c0 = 4 * j;

    const float b_sp = p_sp_bias[0], m_sp = p_sp_amax[0];
    const float b_lo = p_lo_bias[0], m_lo = p_lo_amax[0];
    const float b_mi = p_mi_bias[0], m_mi = p_mi_amax[0];
    const float b_hi = p_hi_bias[0], m_hi = p_hi_amax[0];

    // per-lane channel constants
    float biasK[4], mK[4];
    int gsel[4];  // 0=sp 1=lo 2=mi 3=hi
    #pragma unroll
    for (int k = 0; k < 4; ++k) {
        const int c = c0 + k;
        biasK[k] = c < 3 ? b_sp : (c < 6 ? b_lo : (c < 15 ? b_mi : b_hi));
        mK[k]    = c < 3 ? m_sp : (c < 6 ? m_lo : (c < 15 ? m_mi : m_hi));
        gsel[k]  = c < 3 ? 0 : (c < 6 ? 1 : (c < 15 ? 2 : 3));
    }

    const float Clo = 2.0f * p_lo_alpha[0] * p_lo_gss[0];
    const float Cmi = 2.0f * p_mi_alpha[0] * p_mi_gss[0];
    const float Chi = 2.0f * p_hi_alpha[0] * p_hi_gss[0];
    const float inv_qlo = __fdividef(1.0f, p_lo_psat[0]);
    const float inv_qmi = __fdividef(1.0f, p_mi_psat[0]);
    const float inv_qhi = __fdividef(1.0f, p_hi_psat[0]);
    const float G_sp = 2.0f * p_sp_alpha[0];

    const int wid = blockIdx.x * (blockDim.x >> 6) + (threadIdx.x >> 6);
    const int pix0 = wid * 7;
    if (pix0 >= NPIX) return;
    const int myPix = pix0 + sub;
    const bool valid = act && myPix < NPIX;

    // ---- all lanes: coalesced load of own float4 ----
    float4 x = make_float4(0.f, 0.f, 0.f, 0.f);
    if (valid) x = in4[pix0 * 9 + lane];

    // ---- head lanes: 3x3 box sum of sums -> folded gains ----
    float Gl = 0.f, Gm = 0.f, Gh = 0.f;
    if (j == 0 && valid) {
        const int p = myPix;
        const int px = p & 255, py = (p >> 8) & 255;
        const int rowb = p - px;
        const int xm = max(px - 1, 0), xp = min(px + 1, 255);
        const int rm = rowb - (py > 0 ? 256 : 0);
        const int rp = rowb + (py < 255 ? 256 : 0);
        float slo = 0.f, smi = 0.f, shi = 0.f;
        const int rows[3] = {rm, rowb, rp};
        #pragma unroll
        for (int i = 0; i < 3; ++i) {
            const float4 a = sums[rows[i] + xm];
            const float4 b = sums[rows[i] + px];
            const float4 c = sums[rows[i] + xp];
            slo += a.x + b.x + c.x;
            smi += a.y + b.y + c.y;
            shi += a.z + b.z + c.z;
        }
        Gl = __fdividef(Clo, fmaf(slo, inv_qlo, 1.0f));
        Gm = __fdividef(Cmi, fmaf(smi, inv_qmi, 1.0f));
        Gh = __fdividef(Chi, fmaf(shi, inv_qhi, 1.0f));
    }
    // broadcast from each pixel's head lane (sub*9)
    const int src = sub * 9;
    Gl = __shfl(Gl, src);
    Gm = __shfl(Gm, src);
    Gh = __shfl(Gh, src);

    // ---- transform own 4 channels, coalesced store ----
    if (valid) {
        const float xs[4] = {x.x, x.y, x.z, x.w};
        float o[4];
        #pragma unroll
        for (int k = 0; k < 4; ++k) {
            const float G = gsel[k] == 0 ? G_sp
                          : (gsel[k] == 1 ? Gl : (gsel[k] == 2 ? Gm : Gh));
            // m*tanh(v) = m - 2m/(exp(2v)+1); G already carries the factor 2
            const float e = __expf(G * (xs[k] + biasK[k]));
            o[k] = mK[k] - __fdividef(2.0f * mK[k], e + 1.0f);
        }
        out4[pix0 * 9 + lane] = make_float4(o[0], o[1], o[2], o[3]);
    }
}

extern "C" void kernel_launch(void* const* d_in, const int* in_sizes, int n_in,
                              void* d_out, int out_size, void* d_ws, size_t ws_size,
                              hipStream_t stream) {
    const float4* in4 = (const float4*)d_in[0];
    float4* out4 = (float4*)d_out;
    float4* sums = (float4*)d_ws;     // 8.4 MB scratch

    k1_sums<<<2048, 256, 0, stream>>>(
        in4, sums,
        (const float*)d_in[5], (const float*)d_in[8],     // low bias, eps
        (const float*)d_in[11], (const float*)d_in[14],   // mid bias, eps
        (const float*)d_in[17], (const float*)d_in[20]);  // high bias, eps

    // one sweep: 7 pixels per wave, 4 waves per block
    const int nwaves = (NPIX + 6) / 7;            // 74899
    const int nblocks = (nwaves + 3) / 4;         // 18725
    k2_out<<<nblocks, 256, 0, stream>>>(
        in4, sums, out4,
        (const float*)d_in[1], (const float*)d_in[2], (const float*)d_in[3],
        (const float*)d_in[5], (const float*)d_in[6], (const float*)d_in[7],
        (const float*)d_in[9], (const float*)d_in[10],
        (const float*)d_in[11], (const float*)d_in[12], (const float*)d_in[13],
        (const float*)d_in[15], (const float*)d_in[16],
        (const float*)d_in[17], (const float*)d_in[18], (const float*)d_in[19],
        (const float*)d_in[21], (const float*)d_in[22]);
}

// Round 8
// 56.302 us; speedup vs baseline: 1.0738x; 1.0738x over previous
//
#include <hip/hip_runtime.h>
#include <math.h>

// LocalGroupedZernikeNewBP: fused grouped soft-abs + 3x3 box gain + tanh.
// Layout [B=8, H=256, W=256, C=36] fp32, channel-last.
// Groups: special 0..2 (plain tanh), low 3..5, mid 6..14, high 15..35.
//
// R8: three grid-stride streaming kernels, all K1-shaped (setup amortized).
//  K1 : per-pixel group sums via segmented shfl (lane%9). ~4.5us proven.
//  K15: thread-per-pixel 3x3 box sum of sums -> folded gains (Glo,Gmi,Ghi,Gsp).
//  K2 : wave owns 7 pixels/iter (lane j=lane%9 fixed), grid-stride 2048 blocks
//       -> ~9 iters/wave; gains[p] loaded directly (L1 broadcast, no shfl);
//       per-lane constants hoisted out of the loop.

static constexpr int IMG = 256;
static constexpr int NB = 8;
static constexpr int NPIX = NB * IMG * IMG;   // 524288

__global__ __launch_bounds__(256) void k1_sums(
    const float4* __restrict__ in4, float4* __restrict__ sums,
    const float* __restrict__ pb_lo, const float* __restrict__ pe_lo,
    const float* __restrict__ pb_mi, const float* __restrict__ pe_mi,
    const float* __restrict__ pb_hi, const float* __restrict__ pe_hi)
{
    const float b_lo = pb_lo[0], e_lo = pe_lo[0];
    const float b_mi = pb_mi[0], e_mi = pe_mi[0];
    const float b_hi = pb_hi[0], e_hi = pe_hi[0];

    const int lane = threadIdx.x & 63;
    const int j = lane % 9;                 // quad within pixel
    const bool act = lane < 63;             // lane 63 idle
    const int sub = lane / 9;               // pixel offset within wave's 7
    const int c0 = 4 * j;

    float biasK[4], epsK[4], mLo[4], mMi[4], mHi[4];
    #pragma unroll
    for (int k = 0; k < 4; ++k) {
        const int c = c0 + k;
        biasK[k] = c < 3 ? 0.f : (c < 6 ? b_lo : (c < 15 ? b_mi : b_hi));
        epsK[k]  = c < 6 ? e_lo : (c < 15 ? e_mi : e_hi);
        mLo[k] = (c >= 3 && c < 6) ? 1.f : 0.f;
        mMi[k] = (c >= 6 && c < 15) ? 1.f : 0.f;
        mHi[k] = (c >= 15) ? 1.f : 0.f;
    }

    const int wid = blockIdx.x * (blockDim.x >> 6) + (threadIdx.x >> 6);
    const int nw  = gridDim.x * (blockDim.x >> 6);

    for (int pix0 = wid * 7; pix0 < NPIX; pix0 += nw * 7) {
        const int myPix = pix0 + sub;
        float4 x = make_float4(0.f, 0.f, 0.f, 0.f);
        if (act && myPix < NPIX) x = in4[pix0 * 9 + lane];

        const float xs[4] = {x.x, x.y, x.z, x.w};
        float t[4];
        #pragma unroll
        for (int k = 0; k < 4; ++k) {
            const float u = xs[k] + biasK[k];
            t[k] = sqrtf(fmaf(u, u, epsK[k]));
        }
        float pl = 0.f, pm = 0.f, ph = 0.f;
        #pragma unroll
        for (int k = 0; k < 4; ++k) {
            pl = fmaf(mLo[k], t[k], pl);
            pm = fmaf(mMi[k], t[k], pm);
            ph = fmaf(mHi[k], t[k], ph);
        }
        // segmented reduction: after d=1,2,4,8 lane j covers [j, min(j+2d-1,8)]
        #pragma unroll
        for (int d = 1; d < 16; d <<= 1) {
            const float al = __shfl_down(pl, d);
            const float am = __shfl_down(pm, d);
            const float ah = __shfl_down(ph, d);
            if (j + d < 9) { pl += al; pm += am; ph += ah; }
        }
        if (act && j == 0 && myPix < NPIX)     // lane 63 must NOT store
            sums[myPix] = make_float4(pl, pm, ph, 0.f);
    }
}

__global__ __launch_bounds__(256) void k15_gains(
    const float4* __restrict__ sums, float4* __restrict__ gains,
    const float* __restrict__ p_sp_alpha,
    const float* __restrict__ p_lo_alpha, const float* __restrict__ p_lo_gss,
    const float* __restrict__ p_lo_psat,
    const float* __restrict__ p_mi_alpha, const float* __restrict__ p_mi_gss,
    const float* __restrict__ p_mi_psat,
    const float* __restrict__ p_hi_alpha, const float* __restrict__ p_hi_gss,
    const float* __restrict__ p_hi_psat)
{
    const int p = blockIdx.x * 256 + threadIdx.x;   // exact: 2048*256 = NPIX

    const float Clo = 2.0f * p_lo_alpha[0] * p_lo_gss[0];
    const float Cmi = 2.0f * p_mi_alpha[0] * p_mi_gss[0];
    const float Chi = 2.0f * p_hi_alpha[0] * p_hi_gss[0];
    const float inv_qlo = __fdividef(1.0f, p_lo_psat[0]);
    const float inv_qmi = __fdividef(1.0f, p_mi_psat[0]);
    const float inv_qhi = __fdividef(1.0f, p_hi_psat[0]);
    const float G_sp = 2.0f * p_sp_alpha[0];

    const int x = p & 255, y = (p >> 8) & 255;
    const int rowb = p - x;                                // b*65536 + y*256
    const int xm = max(x - 1, 0), xp = min(x + 1, 255);
    const int rm = rowb - (y > 0 ? 256 : 0);
    const int rp = rowb + (y < 255 ? 256 : 0);

    float slo = 0.f, smi = 0.f, shi = 0.f;
    const int rows[3] = {rm, rowb, rp};
    #pragma unroll
    for (int i = 0; i < 3; ++i) {
        const float4 a = sums[rows[i] + xm];
        const float4 b = sums[rows[i] + x];
        const float4 c = sums[rows[i] + xp];
        slo += a.x + b.x + c.x;
        smi += a.y + b.y + c.y;
        shi += a.z + b.z + c.z;
    }
    const float Gl = __fdividef(Clo, fmaf(slo, inv_qlo, 1.0f));
    const float Gm = __fdividef(Cmi, fmaf(smi, inv_qmi, 1.0f));
    const float Gh = __fdividef(Chi, fmaf(shi, inv_qhi, 1.0f));
    gains[p] = make_float4(Gl, Gm, Gh, G_sp);
}

__global__ __launch_bounds__(256) void k2_out(
    const float4* __restrict__ in4, const float4* __restrict__ gains,
    float4* __restrict__ out4,
    const float* __restrict__ pb_sp, const float* __restrict__ pm_sp,
    const float* __restrict__ pb_lo, const float* __restrict__ pm_lo,
    const float* __restrict__ pb_mi, const float* __restrict__ pm_mi,
    const float* __restrict__ pb_hi, const float* __restrict__ pm_hi)
{
    const int lane = threadIdx.x & 63;
    const int j = lane % 9;                 // fixed channel-quad per lane
    const bool act = lane < 63;
    const int sub = lane / 9;
    const int c0 = 4 * j;

    // hoisted per-lane constants (amortized over ~9 grid-stride iters)
    const float b_sp = pb_sp[0], m_sp = pm_sp[0];
    const float b_lo = pb_lo[0], m_lo = pm_lo[0];
    const float b_mi = pb_mi[0], m_mi = pm_mi[0];
    const float b_hi = pb_hi[0], m_hi = pm_hi[0];
    float biasK[4], mK[4], m2K[4];
    int gsel[4];  // 0=sp(w) 1=lo(x) 2=mi(y) 3=hi(z)
    #pragma unroll
    for (int k = 0; k < 4; ++k) {
        const int c = c0 + k;
        biasK[k] = c < 3 ? b_sp : (c < 6 ? b_lo : (c < 15 ? b_mi : b_hi));
        mK[k]    = c < 3 ? m_sp : (c < 6 ? m_lo : (c < 15 ? m_mi : m_hi));
        m2K[k]   = 2.0f * mK[k];
        gsel[k]  = c < 3 ? 0 : (c < 6 ? 1 : (c < 15 ? 2 : 3));
    }

    const int wid = blockIdx.x * (blockDim.x >> 6) + (threadIdx.x >> 6);
    const int nw  = gridDim.x * (blockDim.x >> 6);

    for (int pix0 = wid * 7; pix0 < NPIX; pix0 += nw * 7) {
        const int myPix = pix0 + sub;
        const bool valid = act && myPix < NPIX;
        if (valid) {
            const float4 x = in4[pix0 * 9 + lane];
            const float4 g = gains[myPix];      // L1 broadcast: 9 lanes share
            const float xs[4] = {x.x, x.y, x.z, x.w};
            float o[4];
            #pragma unroll
            for (int k = 0; k < 4; ++k) {
                const float G = gsel[k] == 0 ? g.w
                              : (gsel[k] == 1 ? g.x : (gsel[k] == 2 ? g.y : g.z));
                // m*tanh(v) = m - 2m/(exp(2v)+1); G carries the factor 2
                const float e = __expf(G * (xs[k] + biasK[k]));
                o[k] = mK[k] - __fdividef(m2K[k], e + 1.0f);
            }
            out4[pix0 * 9 + lane] = make_float4(o[0], o[1], o[2], o[3]);
        }
    }
}

extern "C" void kernel_launch(void* const* d_in, const int* in_sizes, int n_in,
                              void* d_out, int out_size, void* d_ws, size_t ws_size,
                              hipStream_t stream) {
    const float4* in4 = (const float4*)d_in[0];
    float4* out4  = (float4*)d_out;
    float4* sums  = (float4*)d_ws;                   // 8.4 MB
    float4* gains = (float4*)d_ws + NPIX;            // 8.4 MB (ws >= 16.8 MB)

    k1_sums<<<2048, 256, 0, stream>>>(
        in4, sums,
        (const float*)d_in[5], (const float*)d_in[8],     // low bias, eps
        (const float*)d_in[11], (const float*)d_in[14],   // mid bias, eps
        (const float*)d_in[17], (const float*)d_in[20]);  // high bias, eps

    k15_gains<<<NPIX / 256, 256, 0, stream>>>(
        sums, gains,
        (const float*)d_in[2],                            // special alpha
        (const float*)d_in[6], (const float*)d_in[9], (const float*)d_in[10],
        (const float*)d_in[12], (const float*)d_in[15], (const float*)d_in[16],
        (const float*)d_in[18], (const float*)d_in[21], (const float*)d_in[22]);

    k2_out<<<2048, 256, 0, stream>>>(
        in4, gains, out4,
        (const float*)d_in[1], (const float*)d_in[3],     // special bias, amax
        (const float*)d_in[5], (const float*)d_in[7],     // low bias, amax
        (const float*)d_in[11], (const float*)d_in[13],   // mid bias, amax
        (const float*)d_in[17], (const float*)d_in[19]);  // high bias, amax
}